// Round 18
// baseline (56.616 us; speedup 1.0000x reference)
//
#include <hip/hip_runtime.h>

// AffinitySideLoss: B=4, E=12, H=W=512, S=8 offsets, output = 1 float scalar.
// d_in[0] = input_ float32 [4,12,512,512]
// d_in[1] = target int32   [4,1,512,512]
// d_in[2] = offsets int32  [8,2]  (values in [-27,0))
// d_out   = float32 [1]
// d_ws    = per-block partials: float [16][1024]  (64 KB)
//
// R18 = R17 (40.5 us, conflict-free lane=column geometry, VGPR 60) with
// TWO channels staged per phase: barriers 26 -> 14, per-phase compute 2x
// (72 conflict-free ds_read_b32) so the next pair's global loads land
// under a full compute phase, and loads are issued BEFORE the write-
// visibility barrier (WAR within wave is safe: ds_write reads r at issue).
// LDS = 2 x 16,192 B slots (both written each phase, not cross-phase
// double buffering - that was R16's VGPR-120 trap). Same 16x64 tile,
// 1024 blocks x 256 threads, 4 blocks/CU.

typedef float f4 __attribute__((ext_vector_type(4)));

#define HWSZ   262144     // 512*512
#define NE     12
#define NS     8
#define TROWS  16
#define TCOLS  64
#define NBLK   1024       // 4 batches x 32 row-tiles x 8 col-tiles
#define HROWS  44         // rows r0-28 .. r0+15
#define HCOLS  92         // cols c0-28 .. c0+63
#define HSZ    (HROWS * HCOLS)   // 4048 floats
#define NCHUNK (HCOLS / 4)       // 23 f4-chunks per halo row
#define NSLOT  (HSZ / 4)         // 1012 f4 slots per channel
#define QSTEP  (4 * HCOLS)       // 368 floats between a thread's rows

__global__ __launch_bounds__(256) void affloss_main(
    const float* __restrict__ emb, const int* __restrict__ seg,
    const int* __restrict__ offs, float* __restrict__ partial) {
  __shared__ f4 buf4[2 * NSLOT];        // two 16,192 B channel slots
  __shared__ float red[4][16];
  const float* buf0 = (const float*)buf4;
  const float* buf1 = (const float*)(buf4 + NSLOT);

  // XCD swizzle (bijective, 1024 % 8 == 0): contiguous tile band per XCD.
  const int bid = blockIdx.x;
  const int nb  = (bid & 7) * (NBLK / 8) + (bid >> 3);
  const int b   = nb >> 8;              // batch 0..3
  const int rem = nb & 255;             // 32 row-tiles x 8 col-tiles
  const int r0  = (rem >> 3) * TROWS;   // 0..496
  const int c0  = (rem & 7) * TCOLS;    // 0..448

  const int tid  = threadIdx.x;
  const int lane = tid & 63;            // column within tile (stride 4B)
  const int w    = tid >> 6;            // wave 0..3 -> rows w,w+4,w+8,w+12

  const float* embB = emb + (size_t)b * NE * HWSZ;
  const float* segF = (const float*)(seg + (size_t)b * HWSZ);  // bit container

  int soff[NS];                         // halo-space offsets (uniform -> SGPR)
  #pragma unroll
  for (int s = 0; s < NS; ++s)
    soff[s] = offs[2 * s] * HCOLS + offs[2 * s + 1];

  // Staging geometry: f4 slots tid + k*256 (k=0..3; k==3 only tid<244).
  // slot -> halo (row, 4-col chunk); row clamps at 0 (replication); fully-
  // negative col chunk (c0==0, cols<28) splats col 0.
  int srow[4], sgc[4];
  #pragma unroll
  for (int k = 0; k < 4; ++k) {
    const int slot = tid + k * 256;
    const int rr = slot / NCHUNK;
    const int ch = slot - rr * NCHUNK;
    int gr = r0 - 28 + rr; gr = gr < 0 ? 0 : gr;
    srow[k] = gr;
    sgc[k] = c0 - 28 + 4 * ch;
  }
  const bool s3 = tid < (NSLOT - 3 * 256);   // threads 0..243 own slot 4

  auto load_plane = [&](const float* p, f4* r) {
    #pragma unroll
    for (int k = 0; k < 4; ++k) {
      if (k == 3 && !s3) continue;
      const float* rowp = p + srow[k] * 512;
      if (sgc[k] >= 0) {
        r[k] = *reinterpret_cast<const f4*>(rowp + sgc[k]);   // 16B aligned
      } else {
        const float v = rowp[0];                              // replication splat
        r[k] = f4{v, v, v, v};
      }
    }
  };
  auto write_slot = [&](int slot, const f4* r) {
    #pragma unroll
    for (int k = 0; k < 4; ++k) {
      if (k == 3 && !s3) continue;
      buf4[slot * NSLOT + tid + k * 256] = r[k];   // contiguous b128
    }
  };

  float ssv[4][NS];                     // per-row-q, per-sample sum of squares
  #pragma unroll
  for (int q = 0; q < 4; ++q)
    #pragma unroll
    for (int s = 0; s < NS; ++s) ssv[q][s] = 0.f;
  float numa[NS], dena[NS];
  #pragma unroll
  for (int s = 0; s < NS; ++s) { numa[s] = 0.f; dena[s] = 0.f; }

  // center px index for q=0: halo row (28+w), halo col (28+lane)
  const int cb0 = (28 + w) * HCOLS + 28 + lane;

  auto compute_emb = [&](const float* buf) {
    float cc[4];
    #pragma unroll
    for (int q = 0; q < 4; ++q) cc[q] = buf[cb0 + QSTEP * q];
    #pragma unroll
    for (int s = 0; s < NS; ++s) {
      const int a = cb0 + soff[s];     // one VALU add; +QSTEP*q is ds imm
      #pragma unroll
      for (int q = 0; q < 4; ++q) {
        const float sh = buf[a + QSTEP * q];
        const float d = cc[q] - sh;
        ssv[q][s] = fmaf(d, d, ssv[q][s]);
      }
    }
  };

  f4 rA[4], rB[4];
  load_plane(embB, rA);
  load_plane(embB + HWSZ, rB);

  // 7 phases: m=0..5 -> channel pair (2m, 2m+1); m=6 -> seg.
  for (int m = 0; m < 7; ++m) {
    __syncthreads();                   // readers of buf (prev phase) done
    write_slot(0, rA);                 // vmcnt waits land here
    if (m < 6) write_slot(1, rB);
    // issue next phase's loads BEFORE the visibility barrier (WAR-safe)
    if (m < 5) {
      load_plane(embB + (size_t)(2 * m + 2) * HWSZ, rA);
      load_plane(embB + (size_t)(2 * m + 3) * HWSZ, rB);
    } else if (m == 5) {
      load_plane(segF, rA);            // seg bits for the last phase
    }
    __syncthreads();                   // writes visible

    if (m < 6) {
      compute_emb(buf0);
      compute_emb(buf1);
    } else {
      // seg channel (buf0): bit-exact int compare + dice accumulation
      int tc[4];
      #pragma unroll
      for (int q = 0; q < 4; ++q) tc[q] = __float_as_int(buf0[cb0 + QSTEP * q]);
      #pragma unroll
      for (int s = 0; s < NS; ++s) {
        const int a = cb0 + soff[s];
        #pragma unroll
        for (int q = 0; q < 4; ++q) {
          const int t = __float_as_int(buf0[a + QSTEP * q]);
          const float n  = __builtin_amdgcn_sqrtf(ssv[q][s]);
          const float rc = fmaxf(fmaf(n, -(1.0f / 3.0f), 1.0f), 0.0f);
          const float A  = fmaf(-rc, rc, 1.0f);
          const float ta = (tc[q] == t) ? 0.f : 1.f;
          numa[s] = fmaf(A, ta, numa[s]);
          dena[s] += fmaf(A, A, ta);
        }
      }
    }
  }

  // block reduction: [0..7]=num, [8..15]=den
  float arr[16];
  #pragma unroll
  for (int s = 0; s < NS; ++s) { arr[s] = numa[s]; arr[8 + s] = dena[s]; }
  #pragma unroll
  for (int k = 0; k < 16; ++k) {
    float v = arr[k];
    #pragma unroll
    for (int o = 32; o > 0; o >>= 1) v += __shfl_down(v, o, 64);
    arr[k] = v;
  }
  if (lane == 0) {
    #pragma unroll
    for (int k = 0; k < 16; ++k) red[w][k] = arr[k];
  }
  __syncthreads();
  if (tid < 16) {
    float v = red[0][tid] + red[1][tid] + red[2][tid] + red[3][tid];
    partial[tid * NBLK + blockIdx.x] = v;   // [channel][block]
  }
}

__global__ __launch_bounds__(1024) void affloss_final(
    const float* __restrict__ partial, float* __restrict__ out) {
  __shared__ double csum[16];
  const int lane = threadIdx.x & 63, wv = threadIdx.x >> 6;  // wv = channel

  double s = 0.0;
  for (int i = lane; i < NBLK; i += 64)
    s += (double)partial[wv * NBLK + i];
  #pragma unroll
  for (int o = 32; o > 0; o >>= 1) s += __shfl_down(s, o, 64);
  if (lane == 0) csum[wv] = s;
  __syncthreads();

  if (threadIdx.x == 0) {
    double total = 0.0;
    #pragma unroll
    for (int c = 0; c < 8; ++c) {
      double num = csum[c];
      double den = csum[8 + c];
      if (den < 1e-7) den = 1e-7;            // maximum(den, EPS)
      total += 1.0 - 2.0 * num / den;
    }
    out[0] = (float)total;
  }
}

extern "C" void kernel_launch(void* const* d_in, const int* in_sizes, int n_in,
                              void* d_out, int out_size, void* d_ws, size_t ws_size,
                              hipStream_t stream) {
  const float* emb  = (const float*)d_in[0];
  const int*   seg  = (const int*)d_in[1];
  const int*   offs = (const int*)d_in[2];
  float* partial = (float*)d_ws;   // 16*1024 floats = 65,536 B

  affloss_main<<<NBLK, 256, 0, stream>>>(emb, seg, offs, partial);
  affloss_final<<<1, 1024, 0, stream>>>(partial, (float*)d_out);
}

// Round 19
// 56.072 us; speedup vs baseline: 1.0097x; 1.0097x over previous
//
#include <hip/hip_runtime.h>

// AffinitySideLoss: B=4, E=12, H=W=512, S=8 offsets, output = 1 float scalar.
// d_in[0] = input_ float32 [4,12,512,512]
// d_in[1] = target int32   [4,1,512,512]
// d_in[2] = offsets int32  [8,2]  (values in [-27,0))
// d_out   = float32 [1]
// d_ws    = per-block partials: float [16][1024]  (64 KB)
//
// R19 = R18 with the load issue RESTORED to R17's position: after the
// write-visibility barrier, so the loads' implicit vmcnt(0) drain (inside
// the NEXT phase's first __syncthreads) is covered by a full double-length
// compute phase (72 conflict-free ds_read_b32 + VALU). R18's mistake:
// loads issued between the two barriers were force-drained by the second
// __syncthreads -> one exposed L2 round trip inside every phase (+16 us).
// Channel-pairing keeps barriers at 14 (vs R17's 26). Same 16x64 tile,
// lane=column conflict-free geometry, 1024 blocks x 256 threads.

typedef float f4 __attribute__((ext_vector_type(4)));

#define HWSZ   262144     // 512*512
#define NE     12
#define NS     8
#define TROWS  16
#define TCOLS  64
#define NBLK   1024       // 4 batches x 32 row-tiles x 8 col-tiles
#define HROWS  44         // rows r0-28 .. r0+15
#define HCOLS  92         // cols c0-28 .. c0+63
#define HSZ    (HROWS * HCOLS)   // 4048 floats
#define NCHUNK (HCOLS / 4)       // 23 f4-chunks per halo row
#define NSLOT  (HSZ / 4)         // 1012 f4 slots per channel
#define QSTEP  (4 * HCOLS)       // 368 floats between a thread's rows

__global__ __launch_bounds__(256) void affloss_main(
    const float* __restrict__ emb, const int* __restrict__ seg,
    const int* __restrict__ offs, float* __restrict__ partial) {
  __shared__ f4 buf4[2 * NSLOT];        // two 16,192 B channel slots
  __shared__ float red[4][16];
  const float* buf0 = (const float*)buf4;
  const float* buf1 = (const float*)(buf4 + NSLOT);

  // XCD swizzle (bijective, 1024 % 8 == 0): contiguous tile band per XCD.
  const int bid = blockIdx.x;
  const int nb  = (bid & 7) * (NBLK / 8) + (bid >> 3);
  const int b   = nb >> 8;              // batch 0..3
  const int rem = nb & 255;             // 32 row-tiles x 8 col-tiles
  const int r0  = (rem >> 3) * TROWS;   // 0..496
  const int c0  = (rem & 7) * TCOLS;    // 0..448

  const int tid  = threadIdx.x;
  const int lane = tid & 63;            // column within tile (stride 4B)
  const int w    = tid >> 6;            // wave 0..3 -> rows w,w+4,w+8,w+12

  const float* embB = emb + (size_t)b * NE * HWSZ;
  const float* segF = (const float*)(seg + (size_t)b * HWSZ);  // bit container

  int soff[NS];                         // halo-space offsets (uniform -> SGPR)
  #pragma unroll
  for (int s = 0; s < NS; ++s)
    soff[s] = offs[2 * s] * HCOLS + offs[2 * s + 1];

  // Staging geometry: f4 slots tid + k*256 (k=0..3; k==3 only tid<244).
  // slot -> halo (row, 4-col chunk); row clamps at 0 (replication); fully-
  // negative col chunk (c0==0, cols<28) splats col 0.
  int srow[4], sgc[4];
  #pragma unroll
  for (int k = 0; k < 4; ++k) {
    const int slot = tid + k * 256;
    const int rr = slot / NCHUNK;
    const int ch = slot - rr * NCHUNK;
    int gr = r0 - 28 + rr; gr = gr < 0 ? 0 : gr;
    srow[k] = gr;
    sgc[k] = c0 - 28 + 4 * ch;
  }
  const bool s3 = tid < (NSLOT - 3 * 256);   // threads 0..243 own slot 4

  auto load_plane = [&](const float* p, f4* r) {
    #pragma unroll
    for (int k = 0; k < 4; ++k) {
      if (k == 3 && !s3) continue;
      const float* rowp = p + srow[k] * 512;
      if (sgc[k] >= 0) {
        r[k] = *reinterpret_cast<const f4*>(rowp + sgc[k]);   // 16B aligned
      } else {
        const float v = rowp[0];                              // replication splat
        r[k] = f4{v, v, v, v};
      }
    }
  };
  auto write_slot = [&](int slot, const f4* r) {
    #pragma unroll
    for (int k = 0; k < 4; ++k) {
      if (k == 3 && !s3) continue;
      buf4[slot * NSLOT + tid + k * 256] = r[k];   // contiguous b128
    }
  };

  float ssv[4][NS];                     // per-row-q, per-sample sum of squares
  #pragma unroll
  for (int q = 0; q < 4; ++q)
    #pragma unroll
    for (int s = 0; s < NS; ++s) ssv[q][s] = 0.f;
  float numa[NS], dena[NS];
  #pragma unroll
  for (int s = 0; s < NS; ++s) { numa[s] = 0.f; dena[s] = 0.f; }

  // center px index for q=0: halo row (28+w), halo col (28+lane)
  const int cb0 = (28 + w) * HCOLS + 28 + lane;

  auto compute_emb = [&](const float* buf) {
    float cc[4];
    #pragma unroll
    for (int q = 0; q < 4; ++q) cc[q] = buf[cb0 + QSTEP * q];
    #pragma unroll
    for (int s = 0; s < NS; ++s) {
      const int a = cb0 + soff[s];     // one VALU add; +QSTEP*q is ds imm
      #pragma unroll
      for (int q = 0; q < 4; ++q) {
        const float sh = buf[a + QSTEP * q];
        const float d = cc[q] - sh;
        ssv[q][s] = fmaf(d, d, ssv[q][s]);
      }
    }
  };

  f4 rA[4], rB[4];
  load_plane(embB, rA);
  load_plane(embB + HWSZ, rB);

  // 7 phases: m=0..5 -> channel pair (2m, 2m+1); m=6 -> seg.
  for (int m = 0; m < 7; ++m) {
    __syncthreads();                   // readers of prev phase done (+vm drain
                                       //  of loads already covered by compute)
    write_slot(0, rA);                 // rA/rB already complete -> no stall
    if (m < 6) write_slot(1, rB);
    __syncthreads();                   // writes visible

    // issue next phase's loads AFTER the barrier (R17 discipline): they fly
    // under the double compute below; drained at next phase's first barrier.
    if (m < 5) {
      load_plane(embB + (size_t)(2 * m + 2) * HWSZ, rA);
      load_plane(embB + (size_t)(2 * m + 3) * HWSZ, rB);
    } else if (m == 5) {
      load_plane(segF, rA);            // seg bits for the last phase
    }

    if (m < 6) {
      compute_emb(buf0);
      compute_emb(buf1);
    } else {
      // seg channel (buf0): bit-exact int compare + dice accumulation
      int tc[4];
      #pragma unroll
      for (int q = 0; q < 4; ++q) tc[q] = __float_as_int(buf0[cb0 + QSTEP * q]);
      #pragma unroll
      for (int s = 0; s < NS; ++s) {
        const int a = cb0 + soff[s];
        #pragma unroll
        for (int q = 0; q < 4; ++q) {
          const int t = __float_as_int(buf0[a + QSTEP * q]);
          const float n  = __builtin_amdgcn_sqrtf(ssv[q][s]);
          const float rc = fmaxf(fmaf(n, -(1.0f / 3.0f), 1.0f), 0.0f);
          const float A  = fmaf(-rc, rc, 1.0f);
          const float ta = (tc[q] == t) ? 0.f : 1.f;
          numa[s] = fmaf(A, ta, numa[s]);
          dena[s] += fmaf(A, A, ta);
        }
      }
    }
  }

  // block reduction: [0..7]=num, [8..15]=den
  float arr[16];
  #pragma unroll
  for (int s = 0; s < NS; ++s) { arr[s] = numa[s]; arr[8 + s] = dena[s]; }
  #pragma unroll
  for (int k = 0; k < 16; ++k) {
    float v = arr[k];
    #pragma unroll
    for (int o = 32; o > 0; o >>= 1) v += __shfl_down(v, o, 64);
    arr[k] = v;
  }
  if (lane == 0) {
    #pragma unroll
    for (int k = 0; k < 16; ++k) red[w][k] = arr[k];
  }
  __syncthreads();
  if (tid < 16) {
    float v = red[0][tid] + red[1][tid] + red[2][tid] + red[3][tid];
    partial[tid * NBLK + blockIdx.x] = v;   // [channel][block]
  }
}

__global__ __launch_bounds__(1024) void affloss_final(
    const float* __restrict__ partial, float* __restrict__ out) {
  __shared__ double csum[16];
  const int lane = threadIdx.x & 63, wv = threadIdx.x >> 6;  // wv = channel

  double s = 0.0;
  for (int i = lane; i < NBLK; i += 64)
    s += (double)partial[wv * NBLK + i];
  #pragma unroll
  for (int o = 32; o > 0; o >>= 1) s += __shfl_down(s, o, 64);
  if (lane == 0) csum[wv] = s;
  __syncthreads();

  if (threadIdx.x == 0) {
    double total = 0.0;
    #pragma unroll
    for (int c = 0; c < 8; ++c) {
      double num = csum[c];
      double den = csum[8 + c];
      if (den < 1e-7) den = 1e-7;            // maximum(den, EPS)
      total += 1.0 - 2.0 * num / den;
    }
    out[0] = (float)total;
  }
}

extern "C" void kernel_launch(void* const* d_in, const int* in_sizes, int n_in,
                              void* d_out, int out_size, void* d_ws, size_t ws_size,
                              hipStream_t stream) {
  const float* emb  = (const float*)d_in[0];
  const int*   seg  = (const int*)d_in[1];
  const int*   offs = (const int*)d_in[2];
  float* partial = (float*)d_ws;   // 16*1024 floats = 65,536 B

  affloss_main<<<NBLK, 256, 0, stream>>>(emb, seg, offs, partial);
  affloss_final<<<1, 1024, 0, stream>>>(partial, (float*)d_out);
}

// Round 20
// 40.620 us; speedup vs baseline: 1.3938x; 1.3804x over previous
//
#include <hip/hip_runtime.h>

// AffinitySideLoss: B=4, E=12, H=W=512, S=8 offsets, output = 1 float scalar.
// d_in[0] = input_ float32 [4,12,512,512]
// d_in[1] = target int32   [4,1,512,512]
// d_in[2] = offsets int32  [8,2]  (values in [-27,0))
// d_out   = float32 [1]
// d_ws    = per-block partials: float [16][1024]  (64 KB)
//
// R20 = R17 restored verbatim (best of 19 rounds: 40.5 us total, VGPR 60,
// zero bank conflicts, warm-replay invariant). Structure: 16x64 supertile,
// single 16.2 KB LDS halo buffer (44x92 per channel), reg-staged via plain
// f4 loads (global_load_lds bypasses L3 - R6/R8), 2 __syncthreads per
// channel with the next channel's loads issued AFTER both barriers (their
// vmcnt drain at the next phase's first barrier is covered by a full
// compute phase - R18/R19 proved any other placement/pairing regresses via
// exposed drains or VGPR pressure). lane = column -> stride-4B conflict-
// free LDS reads; thread owns rows {w,w+4,w+8,w+12} at constant ds-offset
// immediates. 1024 blocks x 256 threads. Refuted alternatives: direct
// loads (L2-fill cap 43us), L1 tiling (set conflicts), global_load_lds
// (HBM), fused tail (fence invalidates L2), double/triple buffering &
// channel pairing (VGPR cliff), raw-barrier pipelining (codegen spill).

typedef float f4 __attribute__((ext_vector_type(4)));

#define HWSZ   262144     // 512*512
#define NE     12
#define NC     13         // 12 emb channels + 1 seg channel
#define NS     8
#define TROWS  16
#define TCOLS  64
#define NBLK   1024       // 4 batches x 32 row-tiles x 8 col-tiles
#define HROWS  44         // rows r0-28 .. r0+15
#define HCOLS  92         // cols c0-28 .. c0+63
#define HSZ    (HROWS * HCOLS)   // 4048 floats
#define NCHUNK (HCOLS / 4)       // 23 f4-chunks per halo row
#define NSLOT  (HSZ / 4)         // 1012 f4 slots
#define QSTEP  (4 * HCOLS)       // 368 floats between a thread's rows

__global__ __launch_bounds__(256) void affloss_main(
    const float* __restrict__ emb, const int* __restrict__ seg,
    const int* __restrict__ offs, float* __restrict__ partial) {
  __shared__ f4 buf4[NSLOT];            // 16,192 B halo buffer
  __shared__ float red[4][16];
  const float* buf = (const float*)buf4;

  // XCD swizzle (bijective, 1024 % 8 == 0): contiguous tile band per XCD.
  const int bid = blockIdx.x;
  const int nb  = (bid & 7) * (NBLK / 8) + (bid >> 3);
  const int b   = nb >> 8;              // batch 0..3
  const int rem = nb & 255;             // 32 row-tiles x 8 col-tiles
  const int r0  = (rem >> 3) * TROWS;   // 0..496
  const int c0  = (rem & 7) * TCOLS;    // 0..448

  const int tid  = threadIdx.x;
  const int lane = tid & 63;            // column within tile (stride 4B!)
  const int w    = tid >> 6;            // wave 0..3 -> rows w,w+4,w+8,w+12

  const float* embB = emb + (size_t)b * NE * HWSZ;
  const int*   segB = seg + (size_t)b * HWSZ;

  int soff[NS];                         // halo-space offsets (uniform -> SGPR)
  #pragma unroll
  for (int s = 0; s < NS; ++s)
    soff[s] = offs[2 * s] * HCOLS + offs[2 * s + 1];

  // Staging geometry: f4 slots tid + k*256 (k=0..3; k==3 only tid<244).
  // slot -> halo (row, 4-col chunk); row clamps at 0 (replication); fully-
  // negative col chunk (c0==0, cols<28) splats col 0.
  int srow[4], sgc[4];
  #pragma unroll
  for (int k = 0; k < 4; ++k) {
    const int slot = tid + k * 256;
    const int rr = slot / NCHUNK;
    const int ch = slot - rr * NCHUNK;
    int gr = r0 - 28 + rr; gr = gr < 0 ? 0 : gr;
    srow[k] = gr;
    sgc[k] = c0 - 28 + 4 * ch;
  }
  const bool s3 = tid < (NSLOT - 3 * 256);   // threads 0..243 own slot 4

  auto stage_load = [&](int e, f4* r) {
    const float* p = (e < NE) ? (embB + (size_t)e * HWSZ) : (const float*)segB;
    #pragma unroll
    for (int k = 0; k < 4; ++k) {
      if (k == 3 && !s3) continue;
      const float* rowp = p + srow[k] * 512;
      if (sgc[k] >= 0) {
        r[k] = *reinterpret_cast<const f4*>(rowp + sgc[k]);   // 16B aligned
      } else {
        const float v = rowp[0];                              // replication splat
        r[k] = f4{v, v, v, v};
      }
    }
  };
  auto stage_write = [&](const f4* r) {
    #pragma unroll
    for (int k = 0; k < 4; ++k) {
      if (k == 3 && !s3) continue;
      buf4[tid + k * 256] = r[k];       // contiguous b128 (optimal pattern)
    }
  };

  float ssv[4][NS];                     // per-row-q, per-sample sum of squares
  #pragma unroll
  for (int q = 0; q < 4; ++q)
    #pragma unroll
    for (int s = 0; s < NS; ++s) ssv[q][s] = 0.f;
  float numa[NS], dena[NS];
  #pragma unroll
  for (int s = 0; s < NS; ++s) { numa[s] = 0.f; dena[s] = 0.f; }

  // center px index for q=0: halo row (28+w), halo col (28+lane)
  const int cb0 = (28 + w) * HCOLS + 28 + lane;

  f4 r[4];
  stage_load(0, r);

  for (int e = 0; e < NC; ++e) {
    __syncthreads();                   // readers of buf (channel e-1) done
    stage_write(r);                    // waits only on r's loads (vmcnt)
    __syncthreads();                   // writes visible
    if (e + 1 < NC) stage_load(e + 1, r);   // flies during compute below

    if (e < NE) {
      float cc[4];
      #pragma unroll
      for (int q = 0; q < 4; ++q) cc[q] = buf[cb0 + QSTEP * q];
      #pragma unroll
      for (int s = 0; s < NS; ++s) {
        const int a = cb0 + soff[s];   // one VALU add; +QSTEP*q is ds imm
        #pragma unroll
        for (int q = 0; q < 4; ++q) {
          const float sh = buf[a + QSTEP * q];
          const float d = cc[q] - sh;
          ssv[q][s] = fmaf(d, d, ssv[q][s]);
        }
      }
    } else {
      // seg channel: bit-exact int compare + dice accumulation
      int tc[4];
      #pragma unroll
      for (int q = 0; q < 4; ++q) tc[q] = __float_as_int(buf[cb0 + QSTEP * q]);
      #pragma unroll
      for (int s = 0; s < NS; ++s) {
        const int a = cb0 + soff[s];
        #pragma unroll
        for (int q = 0; q < 4; ++q) {
          const int t = __float_as_int(buf[a + QSTEP * q]);
          const float n  = __builtin_amdgcn_sqrtf(ssv[q][s]);
          const float rc = fmaxf(fmaf(n, -(1.0f / 3.0f), 1.0f), 0.0f);
          const float A  = fmaf(-rc, rc, 1.0f);
          const float ta = (tc[q] == t) ? 0.f : 1.f;
          numa[s] = fmaf(A, ta, numa[s]);
          dena[s] += fmaf(A, A, ta);
        }
      }
    }
  }

  // block reduction: [0..7]=num, [8..15]=den
  float arr[16];
  #pragma unroll
  for (int s = 0; s < NS; ++s) { arr[s] = numa[s]; arr[8 + s] = dena[s]; }
  #pragma unroll
  for (int k = 0; k < 16; ++k) {
    float v = arr[k];
    #pragma unroll
    for (int o = 32; o > 0; o >>= 1) v += __shfl_down(v, o, 64);
    arr[k] = v;
  }
  if (lane == 0) {
    #pragma unroll
    for (int k = 0; k < 16; ++k) red[w][k] = arr[k];
  }
  __syncthreads();
  if (tid < 16) {
    float v = red[0][tid] + red[1][tid] + red[2][tid] + red[3][tid];
    partial[tid * NBLK + blockIdx.x] = v;   // [channel][block]
  }
}

__global__ __launch_bounds__(1024) void affloss_final(
    const float* __restrict__ partial, float* __restrict__ out) {
  __shared__ double csum[16];
  const int lane = threadIdx.x & 63, wv = threadIdx.x >> 6;  // wv = channel

  double s = 0.0;
  for (int i = lane; i < NBLK; i += 64)
    s += (double)partial[wv * NBLK + i];
  #pragma unroll
  for (int o = 32; o > 0; o >>= 1) s += __shfl_down(s, o, 64);
  if (lane == 0) csum[wv] = s;
  __syncthreads();

  if (threadIdx.x == 0) {
    double total = 0.0;
    #pragma unroll
    for (int c = 0; c < 8; ++c) {
      double num = csum[c];
      double den = csum[8 + c];
      if (den < 1e-7) den = 1e-7;            // maximum(den, EPS)
      total += 1.0 - 2.0 * num / den;
    }
    out[0] = (float)total;
  }
}

extern "C" void kernel_launch(void* const* d_in, const int* in_sizes, int n_in,
                              void* d_out, int out_size, void* d_ws, size_t ws_size,
                              hipStream_t stream) {
  const float* emb  = (const float*)d_in[0];
  const int*   seg  = (const int*)d_in[1];
  const int*   offs = (const int*)d_in[2];
  float* partial = (float*)d_ws;   // 16*1024 floats = 65,536 B

  affloss_main<<<NBLK, 256, 0, stream>>>(emb, seg, offs, partial);
  affloss_final<<<1, 1024, 0, stream>>>(partial, (float*)d_out);
}